// Round 1
// baseline (306.484 us; speedup 1.0000x reference)
//
#include <hip/hip_runtime.h>

#define NUM_GRAPHS 512
#define NPG 200      // nodes per graph
#define EPG 3200     // edges per graph
#define NROIS 200    // input feature dim
#define HID 64
#define OUTC 2

// LDS budget: 51200 + 6400 + 800 + 1024 + 1024 + 800 + 256 = 61504 B -> 2 blocks/CU
struct Smem {
  float hp[NPG * HID];                              // h' = dinv[i] * (x@W)[i][:]
  union { unsigned short csr[EPG]; float xt[NPG * 8]; } u;  // csr overlays x-tile
  float dinv[NPG];
  int cnt[256];
  int scanb[256];
  int fill[NPG];
  int pool[HID];
};

__global__ __launch_bounds__(256, 2)
void gcn_fused(const float* __restrict__ x,
               const int* __restrict__ ei,
               const float* __restrict__ cw,
               const float* __restrict__ cb,
               const float* __restrict__ lw,
               const float* __restrict__ lb,
               float* __restrict__ out,
               int Etot) {
  __shared__ Smem s;
  const int g = blockIdx.x;
  const int tid = threadIdx.x;
  const int base = g * NPG;
  const int ebase = g * EPG;
  const int j = tid & 63;                               // channel lane
  const int w = __builtin_amdgcn_readfirstlane(tid >> 6);  // wave id (uniform)

  // ---- phase 0: init ----
  s.cnt[tid] = 0;
  if (tid < HID) s.pool[tid] = 0;   // relu output >= 0, so 0 is identity for max
  __syncthreads();

  // ---- phase 1: in-degree count ----
  for (int e = tid; e < EPG; e += 256) {
    int d = ei[Etot + ebase + e] - base;
    atomicAdd(&s.cnt[d], 1);
  }
  __syncthreads();

  // ---- phase 2: inclusive scan (Hillis-Steele over 256) + dinv ----
  {
    int v = s.cnt[tid];
    s.scanb[tid] = v;
    __syncthreads();
    for (int off = 1; off < 256; off <<= 1) {
      int t = 0;
      if (tid >= off) t = s.scanb[tid - off];
      __syncthreads();
      s.scanb[tid] += t;
      __syncthreads();
    }
    if (tid < NPG) {
      int c = s.cnt[tid];
      s.fill[tid] = s.scanb[tid] - c;                 // exclusive offset
      s.dinv[tid] = rsqrtf((float)(c + 1));           // +1 self-loop
    }
  }
  __syncthreads();

  // ---- phase 3: h' = dinv * (x @ W), k tiled by 8 ----
  float acc[50];
  #pragma unroll
  for (int r = 0; r < 50; ++r) acc[r] = 0.f;
  const int iw0 = w * 50;                             // this wave's row block

  for (int k0 = 0; k0 < NROIS; k0 += 8) {
    __syncthreads();   // protect x-tile reuse
    // cooperative stage of x[base..base+199][k0..k0+7] (coalesced float4)
    for (int idx = tid; idx < 400; idx += 256) {
      int i = idx >> 1, q = (idx & 1) << 2;
      const float4 vv = *(const float4*)(x + (size_t)(base + i) * NROIS + k0 + q);
      *(float4*)&s.u.xt[i * 8 + q] = vv;
    }
    // W column chunk in regs (lane j = channel), reused over 50 rows
    float wv[8];
    #pragma unroll
    for (int i = 0; i < 8; ++i) wv[i] = cw[(k0 + i) * HID + j];
    __syncthreads();
    #pragma unroll
    for (int r = 0; r < 50; ++r) {
      const float4 a = *(const float4*)&s.u.xt[(iw0 + r) * 8];
      const float4 b = *(const float4*)&s.u.xt[(iw0 + r) * 8 + 4];
      float c = acc[r];
      c = fmaf(a.x, wv[0], c); c = fmaf(a.y, wv[1], c);
      c = fmaf(a.z, wv[2], c); c = fmaf(a.w, wv[3], c);
      c = fmaf(b.x, wv[4], c); c = fmaf(b.y, wv[5], c);
      c = fmaf(b.z, wv[6], c); c = fmaf(b.w, wv[7], c);
      acc[r] = c;
    }
  }
  __syncthreads();
  #pragma unroll
  for (int r = 0; r < 50; ++r) {
    int i = iw0 + r;
    s.hp[i * HID + j] = s.dinv[i] * acc[r];
  }
  __syncthreads();   // hp ready; xt free for csr overlay

  // ---- phase 4: counting-sort edges into CSR (local src as ushort) ----
  for (int e = tid; e < EPG; e += 256) {
    int sR = ei[ebase + e] - base;
    int d  = ei[Etot + ebase + e] - base;
    int pos = atomicAdd(&s.fill[d], 1);
    s.u.csr[pos] = (unsigned short)sR;
  }
  __syncthreads();

  // ---- phase 5: gather + bias + relu + max-pool ----
  {
    const float cbj = cb[j];
    float mx = 0.f;
    for (int i = w; i < NPG; i += 4) {
      const int end = s.scanb[i];
      int e = end - s.cnt[i];
      float a = s.hp[i * HID + j];                    // self-loop term
      while ((e & 7) && e < end) { a += s.hp[(int)s.u.csr[e] * HID + j]; ++e; }
      for (; e + 8 <= end; e += 8) {
        const uint4 pk = *(const uint4*)&s.u.csr[e];  // 8 edges, broadcast read
        a += s.hp[(int)(pk.x & 0xffffu) * HID + j];
        a += s.hp[(int)(pk.x >> 16)     * HID + j];
        a += s.hp[(int)(pk.y & 0xffffu) * HID + j];
        a += s.hp[(int)(pk.y >> 16)     * HID + j];
        a += s.hp[(int)(pk.z & 0xffffu) * HID + j];
        a += s.hp[(int)(pk.z >> 16)     * HID + j];
        a += s.hp[(int)(pk.w & 0xffffu) * HID + j];
        a += s.hp[(int)(pk.w >> 16)     * HID + j];
      }
      for (; e < end; ++e) a += s.hp[(int)s.u.csr[e] * HID + j];
      float val = fmaf(s.dinv[i], a, cbj);
      val = fmaxf(val, 0.f);
      mx = fmaxf(mx, val);
    }
    atomicMax(&s.pool[j], __float_as_int(mx));
  }
  __syncthreads();

  // ---- phase 6: write x_pool and out = x_pool @ lin_w + lin_b ----
  if (tid < HID) {
    const float xp = __int_as_float(s.pool[tid]);
    out[NUM_GRAPHS * OUTC + g * HID + tid] = xp;      // second output: x_pool
    float p0 = xp * lw[tid * 2 + 0];
    float p1 = xp * lw[tid * 2 + 1];
    #pragma unroll
    for (int off = 32; off > 0; off >>= 1) {
      p0 += __shfl_down(p0, off);
      p1 += __shfl_down(p1, off);
    }
    if (tid == 0) {
      out[g * OUTC + 0] = p0 + lb[0];
      out[g * OUTC + 1] = p1 + lb[1];
    }
  }
}

extern "C" void kernel_launch(void* const* d_in, const int* in_sizes, int n_in,
                              void* d_out, int out_size, void* d_ws, size_t ws_size,
                              hipStream_t stream) {
  const float* x  = (const float*)d_in[0];
  const int*   ei = (const int*)d_in[1];
  // d_in[2] = batch (layout is node/200 by construction; unused)
  const float* cw = (const float*)d_in[3];
  const float* cb = (const float*)d_in[4];
  const float* lw = (const float*)d_in[5];
  const float* lb = (const float*)d_in[6];
  const int Etot = in_sizes[1] / 2;

  gcn_fused<<<NUM_GRAPHS, 256, 0, stream>>>(x, ei, cw, cb, lw, lb, (float*)d_out, Etot);
}

// Round 2
// 196.261 us; speedup vs baseline: 1.5616x; 1.5616x over previous
//
#include <hip/hip_runtime.h>

#define NUM_GRAPHS 512
#define NPG 200      // nodes per graph
#define EPG 3200     // edges per graph
#define NROIS 200    // input feature dim
#define HID 64
#define OUTC 2

typedef short v8s __attribute__((ext_vector_type(8)));
typedef float v4f __attribute__((ext_vector_type(4)));

// LDS: 51200 + 6400 + 800 + 1024 + 1024 + 800 + 256 = 61504 B -> 2 blocks/CU
struct Smem {
  float hp[NPG * HID];        // h' = dinv[i] * (x@W)[i][:]
  unsigned short csr[EPG];    // sorted edge sources (local ids)
  float dinv[NPG];
  int cnt[256];
  int scanb[256];
  int fill[NPG];
  int pool[HID];
};

__device__ __forceinline__ unsigned bf16_rne(float f) {
  unsigned u = __float_as_uint(f);
  return (u + 0x7fffu + ((u >> 16) & 1u)) >> 16;
}

__global__ __launch_bounds__(256, 2)
void gcn_fused(const float* __restrict__ x,
               const int* __restrict__ ei,
               const float* __restrict__ cw,
               const float* __restrict__ cb,
               const float* __restrict__ lw,
               const float* __restrict__ lb,
               float* __restrict__ out,
               int Etot) {
  __shared__ Smem s;
  const int g = blockIdx.x;
  const int tid = threadIdx.x;
  const int base = g * NPG;
  const int ebase = g * EPG;
  const int j = tid & 63;                                  // channel lane
  const int w = __builtin_amdgcn_readfirstlane(tid >> 6);  // wave id 0..3

  // ---- phase 0: init ----
  s.cnt[tid] = 0;
  if (tid < HID) s.pool[tid] = 0;   // relu output >= 0 -> 0 is identity for max
  __syncthreads();

  // ---- phase 1: in-degree count ----
  for (int e = tid; e < EPG; e += 256) {
    int d = ei[Etot + ebase + e] - base;
    atomicAdd(&s.cnt[d], 1);
  }
  __syncthreads();

  // ---- phase 2: inclusive scan (Hillis-Steele over 256) + dinv ----
  {
    int v = s.cnt[tid];
    s.scanb[tid] = v;
    __syncthreads();
    for (int off = 1; off < 256; off <<= 1) {
      int t = 0;
      if (tid >= off) t = s.scanb[tid - off];
      __syncthreads();
      s.scanb[tid] += t;
      __syncthreads();
    }
    if (tid < NPG) {
      int c = s.cnt[tid];
      s.fill[tid] = s.scanb[tid] - c;                 // exclusive offset
      s.dinv[tid] = rsqrtf((float)(c + 1));           // +1 self-loop
    }
  }
  __syncthreads();

  // ---- phase 3: counting-sort edges into CSR (local src as ushort) ----
  for (int e = tid; e < EPG; e += 256) {
    int sR = ei[ebase + e] - base;
    int d  = ei[Etot + ebase + e] - base;
    int pos = atomicAdd(&s.fill[d], 1);
    s.csr[pos] = (unsigned short)sR;
  }
  // no barrier needed yet: csr consumed after the GEMM barrier below

  // ---- phase 4: H = X @ W via bf16 MFMA (hi/lo split for fp32-like accuracy)
  // wave w owns M-tiles [mt0, mt0+mtc); all 4 N-tiles; K tiled by 32.
  {
    const int ml = tid & 15;           // m (A) / n (B) / col (D) within tile
    const int q  = (tid >> 4) & 3;     // k-quad / D-row-group
    const int mt0 = w * 3;             // wave 3 -> tiles 9,10,11,12
    const int mtc = (w == 3) ? 4 : 3;

    v4f acc[4][4];
    #pragma unroll
    for (int a = 0; a < 4; ++a)
      #pragma unroll
      for (int b = 0; b < 4; ++b)
        acc[a][b] = (v4f){0.f, 0.f, 0.f, 0.f};

    for (int kt = 0; kt < 7; ++kt) {
      const int k0 = kt * 32 + q * 8;
      const bool kok = (k0 < NROIS);   // uniform per (kt, q-group)

      // B fragments: B[k][n] with n = ml, k = k0..k0+7 (column reads of W)
      v8s bhi[4], blo[4];
      #pragma unroll
      for (int nt = 0; nt < 4; ++nt) {
        #pragma unroll
        for (int i = 0; i < 8; ++i) {
          float f = kok ? cw[(k0 + i) * HID + nt * 16 + ml] : 0.f;
          unsigned hb = bf16_rne(f);
          float lo = f - __uint_as_float(hb << 16);
          bhi[nt][i] = (short)hb;
          blo[nt][i] = (short)bf16_rne(lo);
        }
      }

      #pragma unroll
      for (int mi = 0; mi < 4; ++mi) {
        if (mi < mtc) {
          const int row = (mt0 + mi) * 16 + ml;
          v8s ahi, alo;
          if (kok && row < NPG) {
            const float* px = x + (size_t)(base + row) * NROIS + k0;
            const float4 v0 = *(const float4*)px;
            const float4 v1 = *(const float4*)(px + 4);
            const float f[8] = {v0.x, v0.y, v0.z, v0.w, v1.x, v1.y, v1.z, v1.w};
            #pragma unroll
            for (int i = 0; i < 8; ++i) {
              unsigned hb = bf16_rne(f[i]);
              float lo = f[i] - __uint_as_float(hb << 16);
              ahi[i] = (short)hb;
              alo[i] = (short)bf16_rne(lo);
            }
          } else {
            #pragma unroll
            for (int i = 0; i < 8; ++i) { ahi[i] = 0; alo[i] = 0; }
          }
          #pragma unroll
          for (int nt = 0; nt < 4; ++nt) {
            acc[mi][nt] = __builtin_amdgcn_mfma_f32_16x16x32_bf16(ahi, blo[nt], acc[mi][nt], 0, 0, 0);
            acc[mi][nt] = __builtin_amdgcn_mfma_f32_16x16x32_bf16(alo, bhi[nt], acc[mi][nt], 0, 0, 0);
            acc[mi][nt] = __builtin_amdgcn_mfma_f32_16x16x32_bf16(ahi, bhi[nt], acc[mi][nt], 0, 0, 0);
          }
        }
      }
    }

    // D layout: row = q*4 + r, col = ml. Write hp = dinv * h.
    #pragma unroll
    for (int mi = 0; mi < 4; ++mi) {
      if (mi < mtc) {
        #pragma unroll
        for (int r = 0; r < 4; ++r) {
          const int row = (mt0 + mi) * 16 + q * 4 + r;
          if (row < NPG) {
            const float dv = s.dinv[row];
            #pragma unroll
            for (int nt = 0; nt < 4; ++nt)
              s.hp[row * HID + nt * 16 + ml] = dv * acc[mi][nt][r];
          }
        }
      }
    }
  }
  __syncthreads();   // hp + csr both ready

  // ---- phase 5: gather + bias + relu + max-pool ----
  {
    const float cbj = cb[j];
    float mx = 0.f;
    for (int i = w; i < NPG; i += 4) {
      const int end = s.scanb[i];
      int e = end - s.cnt[i];
      float a = s.hp[i * HID + j];                    // self-loop term
      while ((e & 7) && e < end) { a += s.hp[(int)s.csr[e] * HID + j]; ++e; }
      for (; e + 8 <= end; e += 8) {
        const uint4 pk = *(const uint4*)&s.csr[e];    // 8 edges, broadcast read
        a += s.hp[(int)(pk.x & 0xffffu) * HID + j];
        a += s.hp[(int)(pk.x >> 16)     * HID + j];
        a += s.hp[(int)(pk.y & 0xffffu) * HID + j];
        a += s.hp[(int)(pk.y >> 16)     * HID + j];
        a += s.hp[(int)(pk.z & 0xffffu) * HID + j];
        a += s.hp[(int)(pk.z >> 16)     * HID + j];
        a += s.hp[(int)(pk.w & 0xffffu) * HID + j];
        a += s.hp[(int)(pk.w >> 16)     * HID + j];
      }
      for (; e < end; ++e) a += s.hp[(int)s.csr[e] * HID + j];
      float val = fmaf(s.dinv[i], a, cbj);
      val = fmaxf(val, 0.f);
      mx = fmaxf(mx, val);
    }
    atomicMax(&s.pool[j], __float_as_int(mx));
  }
  __syncthreads();

  // ---- phase 6: write x_pool and out = x_pool @ lin_w + lin_b ----
  if (tid < HID) {
    const float xp = __int_as_float(s.pool[tid]);
    out[NUM_GRAPHS * OUTC + g * HID + tid] = xp;      // second output: x_pool
    float p0 = xp * lw[tid * 2 + 0];
    float p1 = xp * lw[tid * 2 + 1];
    #pragma unroll
    for (int off = 32; off > 0; off >>= 1) {
      p0 += __shfl_down(p0, off);
      p1 += __shfl_down(p1, off);
    }
    if (tid == 0) {
      out[g * OUTC + 0] = p0 + lb[0];
      out[g * OUTC + 1] = p1 + lb[1];
    }
  }
}

extern "C" void kernel_launch(void* const* d_in, const int* in_sizes, int n_in,
                              void* d_out, int out_size, void* d_ws, size_t ws_size,
                              hipStream_t stream) {
  const float* x  = (const float*)d_in[0];
  const int*   ei = (const int*)d_in[1];
  // d_in[2] = batch (node/200 by construction; unused)
  const float* cw = (const float*)d_in[3];
  const float* cb = (const float*)d_in[4];
  const float* lw = (const float*)d_in[5];
  const float* lb = (const float*)d_in[6];
  const int Etot = in_sizes[1] / 2;

  gcn_fused<<<NUM_GRAPHS, 256, 0, stream>>>(x, ei, cw, cb, lw, lb, (float*)d_out, Etot);
}

// Round 3
// 185.514 us; speedup vs baseline: 1.6521x; 1.0579x over previous
//
#include <hip/hip_runtime.h>

#define NUM_GRAPHS 512
#define NPG 200      // nodes per graph
#define EPG 3200     // edges per graph
#define NROIS 200    // input feature dim
#define HID 64
#define OUTC 2
#define KPAD 224     // padded K for W tiles (multiple of 8, covers k0 up to 216)
#define THREADS 512

typedef short v8s __attribute__((ext_vector_type(8)));
typedef float v4f __attribute__((ext_vector_type(4)));

__device__ __forceinline__ unsigned bf16_rne(float f) {
  unsigned u = __float_as_uint(f);
  return (u + 0x7fffu + ((u >> 16) & 1u)) >> 16;
}

// ---- prep kernel: W -> transposed bf16 hi/lo into ws ([hi: HID*KPAD][lo: HID*KPAD])
__global__ void prep_w(const float* __restrict__ cw, short* __restrict__ ws) {
  int idx = blockIdx.x * 256 + threadIdx.x;
  if (idx >= HID * KPAD) return;
  int ch = idx / KPAD, k = idx - ch * KPAD;
  float f = (k < NROIS) ? cw[k * HID + ch] : 0.f;
  unsigned hi = bf16_rne(f);
  float lo = f - __uint_as_float(hi << 16);
  ws[ch * KPAD + k] = (short)hi;
  ws[HID * KPAD + ch * KPAD + k] = (short)(__float_as_uint(lo) >> 16);
}

// LDS: 25600 + 6400 + 800 + 800 + 800 + 256 = 34656 B
struct Smem {
  unsigned hp[NPG * 32];     // packed bf16: lo16 = ch p, hi16 = ch p+32
  unsigned short csr[EPG];   // sorted edge sources (local ids)
  float dinv[NPG];
  int cnt[NPG];
  int fill[NPG];             // excl offset during sort; == row end after sort
  int pool[HID];
};

__global__ __launch_bounds__(THREADS, 4)
void gcn_fused(const float* __restrict__ x,
               const int* __restrict__ ei,
               const short* __restrict__ wT,   // preconverted W (hi then lo)
               const float* __restrict__ cw,   // fallback if ws too small
               const float* __restrict__ cb,
               const float* __restrict__ lw,
               const float* __restrict__ lb,
               float* __restrict__ out,
               int Etot, int useWs) {
  __shared__ Smem s;
  const int g = blockIdx.x;
  const int tid = threadIdx.x;
  const int base = g * NPG;
  const int ebase = g * EPG;
  const int lane = tid & 63;
  const int w = __builtin_amdgcn_readfirstlane(tid >> 6);  // wave id 0..7

  // ---- init ----
  if (tid < NPG) s.cnt[tid] = 0;
  if (tid < HID) s.pool[tid] = 0;   // relu >= 0 -> 0 is identity for max
  __syncthreads();

  // ---- phase A: load edges into registers + in-degree count ----
  int esrc[7], edst[7];
  #pragma unroll
  for (int r = 0; r < 7; ++r) {
    int e = tid + r * THREADS;
    esrc[r] = -1;
    edst[r] = 0;
    if (e < EPG) {
      esrc[r] = ei[ebase + e] - base;
      edst[r] = ei[Etot + ebase + e] - base;
      atomicAdd(&s.cnt[edst[r]], 1);
    }
  }
  __syncthreads();

  // ---- phase B: exclusive scan + dinv (wave 0, shfl prefix) ----
  if (w == 0) {
    const int l = lane;
    int c0 = 0, c1 = 0, c2 = 0, c3 = 0;
    if (l < 50) {
      c0 = s.cnt[4 * l];     c1 = s.cnt[4 * l + 1];
      c2 = s.cnt[4 * l + 2]; c3 = s.cnt[4 * l + 3];
    }
    const int tot = c0 + c1 + c2 + c3;
    int pre = tot;
    #pragma unroll
    for (int off = 1; off < 64; off <<= 1) {
      int t = __shfl_up(pre, off);
      if (l >= off) pre += t;
    }
    pre -= tot;   // exclusive
    if (l < 50) {
      s.fill[4 * l]     = pre;
      s.fill[4 * l + 1] = pre + c0;
      s.fill[4 * l + 2] = pre + c0 + c1;
      s.fill[4 * l + 3] = pre + c0 + c1 + c2;
      s.dinv[4 * l]     = rsqrtf((float)(c0 + 1));
      s.dinv[4 * l + 1] = rsqrtf((float)(c1 + 1));
      s.dinv[4 * l + 2] = rsqrtf((float)(c2 + 1));
      s.dinv[4 * l + 3] = rsqrtf((float)(c3 + 1));
    }
  }
  __syncthreads();

  // ---- phase C: counting-sort edges into CSR (from registers) ----
  #pragma unroll
  for (int r = 0; r < 7; ++r) {
    if (esrc[r] >= 0) {
      int pos = atomicAdd(&s.fill[edst[r]], 1);
      s.csr[pos] = (unsigned short)esrc[r];
    }
  }
  // no barrier: csr/fill consumed only after the GEMM barrier below

  // ---- phase D: H = X @ W via bf16 MFMA (trunc hi/lo split) ----
  {
    const int ml = tid & 15;           // m (A) / n (B) / col (D) within tile
    const int q  = (tid >> 4) & 3;     // k-quad / D-row-group
    int mts[2];
    mts[0] = w;                        // tiles 0..7
    mts[1] = (w < 5) ? 8 + w : -1;     // tiles 8..12

    v4f acc[2][4];
    #pragma unroll
    for (int a = 0; a < 2; ++a)
      #pragma unroll
      for (int b = 0; b < 4; ++b)
        acc[a][b] = (v4f){0.f, 0.f, 0.f, 0.f};

    for (int kt = 0; kt < 7; ++kt) {
      const int k0 = kt * 32 + q * 8;

      v8s bhi[4], blo[4];
      if (useWs) {
        #pragma unroll
        for (int nt = 0; nt < 4; ++nt) {
          const int ch = nt * 16 + ml;
          bhi[nt] = *(const v8s*)(wT + ch * KPAD + k0);
          blo[nt] = *(const v8s*)(wT + HID * KPAD + ch * KPAD + k0);
        }
      } else {
        const bool kok = (k0 < NROIS);
        #pragma unroll
        for (int nt = 0; nt < 4; ++nt) {
          #pragma unroll
          for (int i = 0; i < 8; ++i) {
            float f = kok ? cw[(k0 + i) * HID + nt * 16 + ml] : 0.f;
            unsigned hb = bf16_rne(f);
            float lo = f - __uint_as_float(hb << 16);
            bhi[nt][i] = (short)hb;
            blo[nt][i] = (short)(__float_as_uint(lo) >> 16);
          }
        }
      }

      #pragma unroll
      for (int mi = 0; mi < 2; ++mi) {
        if (mts[mi] >= 0) {
          const int row = mts[mi] * 16 + ml;
          v8s ahi, alo;
          if (k0 < NROIS && row < NPG) {
            const float* px = x + (size_t)(base + row) * NROIS + k0;
            const float4 f0 = *(const float4*)px;
            const float4 f1 = *(const float4*)(px + 4);
            const float ff[8] = {f0.x, f0.y, f0.z, f0.w, f1.x, f1.y, f1.z, f1.w};
            #pragma unroll
            for (int i = 0; i < 8; ++i) {
              unsigned u = __float_as_uint(ff[i]);
              unsigned hb = u >> 16;                          // trunc hi
              float lo = ff[i] - __uint_as_float(hb << 16);
              ahi[i] = (short)hb;
              alo[i] = (short)(__float_as_uint(lo) >> 16);    // trunc lo
            }
          } else {
            #pragma unroll
            for (int i = 0; i < 8; ++i) { ahi[i] = 0; alo[i] = 0; }
          }
          #pragma unroll
          for (int nt = 0; nt < 4; ++nt) {
            acc[mi][nt] = __builtin_amdgcn_mfma_f32_16x16x32_bf16(ahi, blo[nt], acc[mi][nt], 0, 0, 0);
            acc[mi][nt] = __builtin_amdgcn_mfma_f32_16x16x32_bf16(alo, bhi[nt], acc[mi][nt], 0, 0, 0);
            acc[mi][nt] = __builtin_amdgcn_mfma_f32_16x16x32_bf16(ahi, bhi[nt], acc[mi][nt], 0, 0, 0);
          }
        }
      }
    }

    // epilogue: hp[row][p] = pack(bf16(dinv*h[p]), bf16(dinv*h[p+32]))
    #pragma unroll
    for (int mi = 0; mi < 2; ++mi) {
      if (mts[mi] >= 0) {
        #pragma unroll
        for (int r = 0; r < 4; ++r) {
          const int row = mts[mi] * 16 + q * 4 + r;
          if (row < NPG) {
            const float dv = s.dinv[row];
            #pragma unroll
            for (int nt2 = 0; nt2 < 2; ++nt2) {
              unsigned u0 = bf16_rne(dv * acc[mi][nt2][r]);
              unsigned u1 = bf16_rne(dv * acc[mi][nt2 + 2][r]);
              s.hp[row * 32 + nt2 * 16 + ml] = u0 | (u1 << 16);
            }
          }
        }
      }
    }
  }
  __syncthreads();   // hp, csr, fill all ready

  // ---- phase E: gather + bias + relu + max-pool ----
  {
    const int es = lane >> 5;          // edge slot 0/1
    const int p = lane & 31;           // channel pair
    const float cb0 = cb[p];
    const float cb1 = cb[p + 32];
    float mx0 = 0.f, mx1 = 0.f;

    for (int ii = w; ii < NPG; ii += 8) {
      const int end = s.fill[ii];
      const int d = s.cnt[ii];
      const int start = end - d;

      int myed = 0;
      if (lane < d) myed = (int)s.csr[start + lane];   // edge list -> lane regs

      const unsigned su = s.hp[ii * 32 + p];           // self-loop
      float a0 = 0.f, a1 = 0.f;
      if (es == 0) {
        a0 = __uint_as_float(su << 16);
        a1 = __uint_as_float(su & 0xffff0000u);
      }

      const int dcap = d < 64 ? d : 64;
      int e = 0;
      for (; e + 2 <= dcap; e += 2) {                  // uniform scalar loop
        int s0 = __builtin_amdgcn_readlane(myed, e);
        int s1 = __builtin_amdgcn_readlane(myed, e + 1);
        int src = es ? s1 : s0;
        unsigned v = s.hp[src * 32 + p];
        a0 += __uint_as_float(v << 16);
        a1 += __uint_as_float(v & 0xffff0000u);
      }
      if (e < dcap) {                                  // odd leftover
        int s0 = __builtin_amdgcn_readlane(myed, e);
        if (es == 0) {
          unsigned v = s.hp[s0 * 32 + p];
          a0 += __uint_as_float(v << 16);
          a1 += __uint_as_float(v & 0xffff0000u);
        }
      }
      for (int e2 = 64; e2 < d; ++e2) {                // deg>64: ~never
        int src = (int)s.csr[start + e2];
        if (es == 0) {
          unsigned v = s.hp[src * 32 + p];
          a0 += __uint_as_float(v << 16);
          a1 += __uint_as_float(v & 0xffff0000u);
        }
      }

      a0 += __shfl_xor(a0, 32);
      a1 += __shfl_xor(a1, 32);
      const float dv = s.dinv[ii];
      mx0 = fmaxf(mx0, fmaxf(fmaf(dv, a0, cb0), 0.f));
      mx1 = fmaxf(mx1, fmaxf(fmaf(dv, a1, cb1), 0.f));
    }
    if (es == 0) {
      atomicMax(&s.pool[p],      __float_as_int(mx0));
      atomicMax(&s.pool[p + 32], __float_as_int(mx1));
    }
  }
  __syncthreads();

  // ---- phase F: write x_pool and out = x_pool @ lin_w + lin_b ----
  if (tid < HID) {
    const float xp = __int_as_float(s.pool[tid]);
    out[NUM_GRAPHS * OUTC + g * HID + tid] = xp;
    float p0 = xp * lw[tid * 2 + 0];
    float p1 = xp * lw[tid * 2 + 1];
    #pragma unroll
    for (int off = 32; off > 0; off >>= 1) {
      p0 += __shfl_down(p0, off);
      p1 += __shfl_down(p1, off);
    }
    if (tid == 0) {
      out[g * OUTC + 0] = p0 + lb[0];
      out[g * OUTC + 1] = p1 + lb[1];
    }
  }
}

extern "C" void kernel_launch(void* const* d_in, const int* in_sizes, int n_in,
                              void* d_out, int out_size, void* d_ws, size_t ws_size,
                              hipStream_t stream) {
  const float* x  = (const float*)d_in[0];
  const int*   ei = (const int*)d_in[1];
  // d_in[2] = batch (node/200 by construction; unused)
  const float* cw = (const float*)d_in[3];
  const float* cb = (const float*)d_in[4];
  const float* lw = (const float*)d_in[5];
  const float* lb = (const float*)d_in[6];
  const int Etot = in_sizes[1] / 2;

  const size_t wsNeeded = (size_t)2 * HID * KPAD * sizeof(short);
  const int useWs = (ws_size >= wsNeeded) ? 1 : 0;
  if (useWs) {
    prep_w<<<(HID * KPAD + 255) / 256, 256, 0, stream>>>(cw, (short*)d_ws);
  }
  gcn_fused<<<NUM_GRAPHS, THREADS, 0, stream>>>(x, ei, (const short*)d_ws, cw,
                                                cb, lw, lb, (float*)d_out, Etot, useWs);
}

// Round 4
// 163.957 us; speedup vs baseline: 1.8693x; 1.1315x over previous
//
#include <hip/hip_runtime.h>

#define NUM_GRAPHS 512
#define NPG 200      // nodes per graph
#define EPG 3200     // edges per graph
#define NROIS 200    // input feature dim
#define HID 64
#define OUTC 2
#define KPAD 224     // padded K for W tiles
#define THREADS 512
#define APITCH 232   // adjacency row pitch (bytes); 232B=58dw, 58 mod 32=26 -> 16 distinct banks
#define HPITCH 232   // hpT row pitch (bf16 elems); 464B=116dw, 116 mod 32=20 -> 2-way (free)

typedef short v8s __attribute__((ext_vector_type(8)));
typedef float v4f __attribute__((ext_vector_type(4)));

__device__ __forceinline__ unsigned bf16_rne(float f) {
  unsigned u = __float_as_uint(f);
  return (u + 0x7fffu + ((u >> 16) & 1u)) >> 16;
}

// ---- prep kernel: W -> transposed bf16 hi/lo into ws ----
__global__ void prep_w(const float* __restrict__ cw, short* __restrict__ ws) {
  int idx = blockIdx.x * 256 + threadIdx.x;
  if (idx >= HID * KPAD) return;
  int ch = idx / KPAD, k = idx - ch * KPAD;
  float f = (k < NROIS) ? cw[k * HID + ch] : 0.f;
  unsigned hi = bf16_rne(f);
  float lo = f - __uint_as_float(hi << 16);
  ws[ch * KPAD + k] = (short)hi;
  ws[HID * KPAD + ch * KPAD + k] = (short)(__float_as_uint(lo) >> 16);
}

// LDS: 48256 + 29696 + 800 + 800 + 256 = 79808 B -> 2 blocks/CU
struct __align__(16) Smem {
  unsigned char adj[208 * APITCH];   // (A+I) counts as bytes; rows 200..207 & cols 200..231 stay 0
  unsigned short hpT[HID * HPITCH]; // bf16 of dinv[node]*h[node][ch], transposed [ch][node]
  float dinv[NPG];
  int cnt[NPG];
  int pool[HID];
};

__global__ __launch_bounds__(THREADS, 4)
void gcn_fused(const float* __restrict__ x,
               const int* __restrict__ ei,
               const short* __restrict__ wT,
               const float* __restrict__ cw,
               const float* __restrict__ cb,
               const float* __restrict__ lw,
               const float* __restrict__ lb,
               float* __restrict__ out,
               int Etot, int useWs) {
  __shared__ Smem s;
  const int g = blockIdx.x;
  const int tid = threadIdx.x;
  const int base = g * NPG;
  const int ebase = g * EPG;
  const int lane = tid & 63;
  const int w = __builtin_amdgcn_readfirstlane(tid >> 6);  // wave id 0..7
  const int ml = tid & 15;
  const int q  = (tid >> 4) & 3;

  // ---- phase 0: zero adj + hpT (contiguous, uint4), cnt, pool ----
  {
    uint4* z = (uint4*)&s;
    const uint4 z4 = {0u, 0u, 0u, 0u};
    #pragma unroll
    for (int i = 0; i < 10; ++i) {
      int idx = tid + i * THREADS;
      if (idx < (208 * APITCH + HID * HPITCH * 2) / 16) z[idx] = z4;
    }
    if (tid < NPG) s.cnt[tid] = 0;
    if (tid < HID) s.pool[tid] = 0;   // relu >= 0 -> 0 is identity for max
  }
  __syncthreads();

  // ---- phase A: load edges to registers + in-degree count ----
  int esrc[7], edst[7];
  #pragma unroll
  for (int r = 0; r < 7; ++r) {
    int e = tid + r * THREADS;
    esrc[r] = -1; edst[r] = 0;
    if (e < EPG) {
      esrc[r] = ei[ebase + e] - base;
      edst[r] = ei[Etot + ebase + e] - base;
      atomicAdd(&s.cnt[edst[r]], 1);
    }
  }
  __syncthreads();

  // ---- phase B: dinv = rsqrt(deg+1) (wave 0) ----
  if (w == 0) {
    if (lane < 50) {
      #pragma unroll
      for (int t = 0; t < 4; ++t) {
        int i = 4 * lane + t;
        s.dinv[i] = rsqrtf((float)(s.cnt[i] + 1));
      }
    }
  }

  // ---- phase C: scatter (A+I) into byte-count matrix (dup-safe packed atomics) ----
  {
    unsigned* adjW = (unsigned*)s.adj;
    #pragma unroll
    for (int r = 0; r < 7; ++r) {
      if (esrc[r] >= 0) {
        int idx = edst[r] * APITCH + esrc[r];
        atomicAdd(&adjW[idx >> 2], 1u << ((idx & 3) * 8));
      }
    }
    if (tid < NPG) {  // self-loop on diagonal
      int idx = tid * APITCH + tid;
      atomicAdd(&adjW[idx >> 2], 1u << ((idx & 3) * 8));
    }
  }
  __syncthreads();   // dinv ready for GEMM1 epilogue; adj ready for GEMM2

  // ---- phase D: H = X @ W via bf16 MFMA (trunc hi/lo split), write hpT ----
  {
    int mts[2];
    mts[0] = w;
    mts[1] = (w < 5) ? 8 + w : -1;

    v4f acc[2][4];
    #pragma unroll
    for (int a = 0; a < 2; ++a)
      #pragma unroll
      for (int b = 0; b < 4; ++b)
        acc[a][b] = (v4f){0.f, 0.f, 0.f, 0.f};

    for (int kt = 0; kt < 7; ++kt) {
      const int k0 = kt * 32 + q * 8;

      v8s bhi[4], blo[4];
      if (useWs) {
        #pragma unroll
        for (int nt = 0; nt < 4; ++nt) {
          const int ch = nt * 16 + ml;
          bhi[nt] = *(const v8s*)(wT + ch * KPAD + k0);
          blo[nt] = *(const v8s*)(wT + HID * KPAD + ch * KPAD + k0);
        }
      } else {
        const bool kok = (k0 < NROIS);
        #pragma unroll
        for (int nt = 0; nt < 4; ++nt) {
          #pragma unroll
          for (int i = 0; i < 8; ++i) {
            float f = kok ? cw[(k0 + i) * HID + nt * 16 + ml] : 0.f;
            unsigned hb = bf16_rne(f);
            float lo = f - __uint_as_float(hb << 16);
            bhi[nt][i] = (short)hb;
            blo[nt][i] = (short)(__float_as_uint(lo) >> 16);
          }
        }
      }

      #pragma unroll
      for (int mi = 0; mi < 2; ++mi) {
        if (mts[mi] >= 0) {
          const int row = mts[mi] * 16 + ml;
          v8s ahi, alo;
          if (k0 < NROIS && row < NPG) {
            const float* px = x + (size_t)(base + row) * NROIS + k0;
            const float4 f0 = *(const float4*)px;
            const float4 f1 = *(const float4*)(px + 4);
            const float ff[8] = {f0.x, f0.y, f0.z, f0.w, f1.x, f1.y, f1.z, f1.w};
            #pragma unroll
            for (int i = 0; i < 8; ++i) {
              unsigned u = __float_as_uint(ff[i]);
              unsigned hb = u >> 16;
              float lo = ff[i] - __uint_as_float(hb << 16);
              ahi[i] = (short)hb;
              alo[i] = (short)(__float_as_uint(lo) >> 16);
            }
          } else {
            #pragma unroll
            for (int i = 0; i < 8; ++i) { ahi[i] = 0; alo[i] = 0; }
          }
          #pragma unroll
          for (int nt = 0; nt < 4; ++nt) {
            acc[mi][nt] = __builtin_amdgcn_mfma_f32_16x16x32_bf16(ahi, blo[nt], acc[mi][nt], 0, 0, 0);
            acc[mi][nt] = __builtin_amdgcn_mfma_f32_16x16x32_bf16(alo, bhi[nt], acc[mi][nt], 0, 0, 0);
            acc[mi][nt] = __builtin_amdgcn_mfma_f32_16x16x32_bf16(ahi, bhi[nt], acc[mi][nt], 0, 0, 0);
          }
        }
      }
    }

    // epilogue: hpT[ch][row] = bf16(dinv[row] * h)
    #pragma unroll
    for (int mi = 0; mi < 2; ++mi) {
      if (mts[mi] >= 0) {
        #pragma unroll
        for (int r = 0; r < 4; ++r) {
          const int row = mts[mi] * 16 + q * 4 + r;
          if (row < NPG) {
            const float dv = s.dinv[row];
            #pragma unroll
            for (int nt = 0; nt < 4; ++nt)
              s.hpT[(nt * 16 + ml) * HPITCH + row] =
                  (unsigned short)bf16_rne(dv * acc[mi][nt][r]);
          }
        }
      }
    }
  }
  __syncthreads();   // hpT + adj ready

  // ---- phase E: AGG = (A+I) @ hp via bf16 MFMA (adjacency ints exact in bf16) ----
  {
    int mts[2];
    mts[0] = w;
    mts[1] = (w < 5) ? 8 + w : -1;

    v4f acc2[2][4];
    #pragma unroll
    for (int a = 0; a < 2; ++a)
      #pragma unroll
      for (int b = 0; b < 4; ++b)
        acc2[a][b] = (v4f){0.f, 0.f, 0.f, 0.f};

    for (int kt = 0; kt < 7; ++kt) {
      const int k0 = kt * 32 + q * 8;     // k0 up to 216, reads to 224 <= 232 (zero pad)

      v8s bf[4];
      #pragma unroll
      for (int nt = 0; nt < 4; ++nt)
        bf[nt] = *(const v8s*)&s.hpT[(nt * 16 + ml) * HPITCH + k0];

      #pragma unroll
      for (int mi = 0; mi < 2; ++mi) {
        if (mts[mi] >= 0) {
          const int row = mts[mi] * 16 + ml;
          const uint2 dd = *(const uint2*)&s.adj[row * APITCH + k0];
          v8s af;
          #pragma unroll
          for (int i = 0; i < 4; ++i) {
            af[i]     = (short)(__float_as_uint((float)((dd.x >> (8 * i)) & 0xffu)) >> 16);
            af[i + 4] = (short)(__float_as_uint((float)((dd.y >> (8 * i)) & 0xffu)) >> 16);
          }
          #pragma unroll
          for (int nt = 0; nt < 4; ++nt)
            acc2[mi][nt] = __builtin_amdgcn_mfma_f32_16x16x32_bf16(af, bf[nt], acc2[mi][nt], 0, 0, 0);
        }
      }
    }

    // epilogue: val = relu(dinv[dst]*agg + cb[ch]); max-pool over rows
    float cbv[4];
    #pragma unroll
    for (int nt = 0; nt < 4; ++nt) cbv[nt] = cb[nt * 16 + ml];
    float mx[4] = {0.f, 0.f, 0.f, 0.f};
    #pragma unroll
    for (int mi = 0; mi < 2; ++mi) {
      if (mts[mi] >= 0) {
        #pragma unroll
        for (int r = 0; r < 4; ++r) {
          const int row = mts[mi] * 16 + q * 4 + r;
          if (row < NPG) {
            const float dv = s.dinv[row];
            #pragma unroll
            for (int nt = 0; nt < 4; ++nt) {
              float v = fmaxf(fmaf(dv, acc2[mi][nt][r], cbv[nt]), 0.f);
              mx[nt] = fmaxf(mx[nt], v);
            }
          }
        }
      }
    }
    #pragma unroll
    for (int nt = 0; nt < 4; ++nt) {
      mx[nt] = fmaxf(mx[nt], __shfl_xor(mx[nt], 16));
      mx[nt] = fmaxf(mx[nt], __shfl_xor(mx[nt], 32));
    }
    if (q == 0 && (lane >> 5) == 0) {
      #pragma unroll
      for (int nt = 0; nt < 4; ++nt)
        atomicMax(&s.pool[nt * 16 + ml], __float_as_int(mx[nt]));
    }
  }
  __syncthreads();

  // ---- phase F: write x_pool and out = x_pool @ lin_w + lin_b ----
  if (tid < HID) {
    const float xp = __int_as_float(s.pool[tid]);
    out[NUM_GRAPHS * OUTC + g * HID + tid] = xp;
    float p0 = xp * lw[tid * 2 + 0];
    float p1 = xp * lw[tid * 2 + 1];
    #pragma unroll
    for (int off = 32; off > 0; off >>= 1) {
      p0 += __shfl_down(p0, off);
      p1 += __shfl_down(p1, off);
    }
    if (tid == 0) {
      out[g * OUTC + 0] = p0 + lb[0];
      out[g * OUTC + 1] = p1 + lb[1];
    }
  }
}

extern "C" void kernel_launch(void* const* d_in, const int* in_sizes, int n_in,
                              void* d_out, int out_size, void* d_ws, size_t ws_size,
                              hipStream_t stream) {
  const float* x  = (const float*)d_in[0];
  const int*   ei = (const int*)d_in[1];
  // d_in[2] = batch (node/200 by construction; unused)
  const float* cw = (const float*)d_in[3];
  const float* cb = (const float*)d_in[4];
  const float* lw = (const float*)d_in[5];
  const float* lb = (const float*)d_in[6];
  const int Etot = in_sizes[1] / 2;

  const size_t wsNeeded = (size_t)2 * HID * KPAD * sizeof(short);
  const int useWs = (ws_size >= wsNeeded) ? 1 : 0;
  if (useWs) {
    prep_w<<<(HID * KPAD + 255) / 256, 256, 0, stream>>>(cw, (short*)d_ws);
  }
  gcn_fused<<<NUM_GRAPHS, THREADS, 0, stream>>>(x, ei, (const short*)d_ws, cw,
                                                cb, lw, lb, (float*)d_out, Etot, useWs);
}